// Round 13
// baseline (101.534 us; speedup 1.0000x reference)
//
#include <hip/hip_runtime.h>
#include <hip/hip_bf16.h>

// Conv2DAttentionBlock: B=16, C=128, HW=1024, 4 heads x d=128 attention + 1x1 convs.
// All GEMM-shaped stages in bf16 MFMA, fp32 accumulate.
// Workspace layout (needs 71,827,456 bytes):
//   wqkv  bf16[1536][128]           @ 0           (Wq rows pre-scaled by 1/sqrt(128)*log2e)
//   wtb   bf16[128][512]            @ 393216
//   xt    bf16[16][1024][128]       @ 524288      (x transposed, n-major)
//   Qt    bf16[16][4][1024][128]    @ 4718592     (n-major, pre-scaled)
//   Kt    bf16[16][4][1024][128]    @ 21495808    (m-major)
//   Vd    bf16[16][4][128][1024]    @ 38273024    (d-major)
//   Oscr  bf16[16][1024][512]       @ 55050240    (scrambled-transposed attn out)

#define NB 16
#define CD 128
#define HWN 1024
#define NH 4
#define KVB 64

typedef __attribute__((ext_vector_type(8))) short bf16x8;
typedef __attribute__((ext_vector_type(4))) short bf16x4;
typedef __attribute__((ext_vector_type(4))) float f32x4;
typedef __attribute__((ext_vector_type(16))) float f32x16;

static __device__ __forceinline__ short f2bf(float f) {
  union { float f; unsigned u; } v; v.f = f;
  unsigned r = v.u + 0x7fffu + ((v.u >> 16) & 1u);  // RNE
  return (short)(r >> 16);
}

// pack 2 f32 -> dword of 2 bf16 (lo = a, hi = b)
static __device__ __forceinline__ unsigned pk2(float a, float b) {
  unsigned r;
  asm("v_cvt_pk_bf16_f32 %0, %1, %2" : "=v"(r) : "v"(a), "v"(b));
  return r;
}

// pack 4 f32 -> 4 bf16
static __device__ __forceinline__ bf16x4 pk4(float a0, float a1, float a2, float a3) {
  union { unsigned u[2]; bf16x4 s; } r;
  r.u[0] = pk2(a0, a1);
  r.u[1] = pk2(a2, a3);
  return r.s;
}

// v_permlane32_swap_b32 a, b:  a' = {a_lo, b_lo},  b' = {a_hi, b_hi}
#define PSWAP(a, b) asm("v_permlane32_swap_b32 %0, %1" : "+v"(a), "+v"(b))

// exchange with lane^32: returns partner's x
static __device__ __forceinline__ float xswap32(float x, int lane) {
  union { float f; unsigned u; } a, b;
  a.f = x; b.f = x;
  PSWAP(a.u, b.u);
  return (lane < 32) ? b.f : a.f;
}

// ---- prep: weights fp32->bf16 (z==16) + x transpose (z<16) --------------
__global__ void prep(const float* __restrict__ x, const float* __restrict__ Wq,
                     const float* __restrict__ Wk, const float* __restrict__ Wv,
                     const float* __restrict__ Wt,
                     short* __restrict__ wqkv, short* __restrict__ wtb,
                     short* __restrict__ xt) {
  __shared__ short tile[32][33];  // tile[c_local][n_local], +1 pad
  if (blockIdx.z == 16) {
    const float SC = 0.08838834764831845f * 1.44269504088896341f;  // 1/sqrt(128)*log2(e)
    int gid = (blockIdx.x * 4 + blockIdx.y) * 256 + threadIdx.x;   // 0..32767
#pragma unroll
    for (int t = 0; t < 2; ++t) {
      int i = gid + t * 32768;
      wqkv[i]          = f2bf(Wq[i] * SC);
      wqkv[i + 65536]  = f2bf(Wk[i]);
      wqkv[i + 131072] = f2bf(Wv[i]);
      wtb[i]           = f2bf(Wt[i]);
    }
    return;
  }
  int b = blockIdx.z, c0 = blockIdx.y * 32, n0 = blockIdx.x * 32;
  int tx = threadIdx.x & 31, ty = threadIdx.x >> 5;  // 32x8
  const float* xp = x + ((size_t)b * CD + c0) * HWN + n0;
  for (int k = 0; k < 4; ++k)
    tile[ty + 8 * k][tx] = f2bf(xp[(size_t)(ty + 8 * k) * HWN + tx]);
  __syncthreads();
  int nl = threadIdx.x >> 3, cq = (threadIdx.x & 7) * 4;
  bf16x4 v4;
#pragma unroll
  for (int k = 0; k < 4; ++k) v4[k] = tile[cq + k][nl];
  *(bf16x4*)(xt + ((size_t)b * HWN + n0 + nl) * CD + c0 + cq) = v4;
}

// ---- QKV: Y[o][n] = sum_c Wqkv[o][c] * x[c][n]; scatter to Qt/Kt/Vd -----
// (R10-proven: LDS-staged x-tile, XCD chunk swizzle)
__launch_bounds__(256)
__global__ void qkv_gemm(const short* __restrict__ wqkv, const short* __restrict__ xt,
                         const float* __restrict__ bv,
                         short* __restrict__ Qt, short* __restrict__ Kt,
                         short* __restrict__ Vd) {
  int wid = blockIdx.x;
  int work = (wid & 7) * 192 + (wid >> 3);  // bijective: 1536 = 8 * 192
  int b = work / 96;
  int rem = work - b * 96;
  int oy = rem >> 3;   // 0..11 -> o-tile of 128
  int nx = rem & 7;    // 0..7  -> n-tile of 128

  int wave = threadIdx.x >> 6, lane = threadIdx.x & 63;
  int l15 = lane & 15, l4 = lane >> 4;
  int o0 = oy * 128 + wave * 32;
  int n0 = nx * 128;
  bool isV = (oy >= 8);  // uniform per block

  __shared__ short Xls[128 * CD];  // 32KB, rows XOR-swizzled (byte^=(row&7)<<4)

  for (int j = 0; j < 8; ++j) {
    int ii = wave * 8 + j;
    int row = ii * 4 + l4;
    int scol = (l15 * 16) ^ ((row & 7) << 4);
    const short* gp = xt + ((size_t)b * HWN + n0 + row) * CD + (scol >> 1);
    __builtin_amdgcn_global_load_lds(
        (const __attribute__((address_space(1))) void*)gp,
        (__attribute__((address_space(3))) void*)&Xls[ii * 512], 16, 0, 0);
  }

  bf16x8 afrag[2][4];
  for (int of = 0; of < 2; ++of)
    for (int kt = 0; kt < 4; ++kt)
      afrag[of][kt] = *(const bf16x8*)(wqkv + (size_t)(o0 + of * 16 + l15) * CD + kt * 32 + l4 * 8);

  f32x4 acc[2][8];
  for (int of = 0; of < 2; ++of)
    for (int jt = 0; jt < 8; ++jt) acc[of][jt] = (f32x4){0.f, 0.f, 0.f, 0.f};

  __syncthreads();  // staging complete (drains vmcnt)

  if (!isV) {
    __builtin_amdgcn_s_setprio(1);
    for (int jt = 0; jt < 8; ++jt) {
      int rb = (jt * 16 + l15) * CD;
      for (int kt = 0; kt < 4; ++kt) {
        bf16x8 bfrag = *(const bf16x8*)&Xls[rb + ((kt * 32 + l4 * 8) ^ ((l15 & 7) << 3))];
        acc[0][jt] = __builtin_amdgcn_mfma_f32_16x16x32_bf16(afrag[0][kt], bfrag, acc[0][jt], 0, 0, 0);
        acc[1][jt] = __builtin_amdgcn_mfma_f32_16x16x32_bf16(afrag[1][kt], bfrag, acc[1][jt], 0, 0, 0);
      }
    }
    __builtin_amdgcn_s_setprio(0);
    short* dst = (o0 < 512) ? Qt : Kt;
    int oo = (o0 < 512) ? o0 : o0 - 512;
    for (int of = 0; of < 2; ++of) {
      int h = (oo + of * 16) >> 7, d0 = ((oo + of * 16) & 127) + l4 * 4;
      for (int jt = 0; jt < 8; ++jt) {
        int n = n0 + jt * 16 + l15;
        *(bf16x4*)(dst + (((size_t)b * NH + h) * HWN + n) * CD + d0) =
            pk4(acc[of][jt][0], acc[of][jt][1], acc[of][jt][2], acc[of][jt][3]);
      }
    }
  } else {
    __builtin_amdgcn_s_setprio(1);
    for (int jt = 0; jt < 8; ++jt) {
      int rb = (jt * 16 + l15) * CD;
      for (int kt = 0; kt < 4; ++kt) {
        bf16x8 bfrag = *(const bf16x8*)&Xls[rb + ((kt * 32 + l4 * 8) ^ ((l15 & 7) << 3))];
        acc[0][jt] = __builtin_amdgcn_mfma_f32_16x16x32_bf16(bfrag, afrag[0][kt], acc[0][jt], 0, 0, 0);
        acc[1][jt] = __builtin_amdgcn_mfma_f32_16x16x32_bf16(bfrag, afrag[1][kt], acc[1][jt], 0, 0, 0);
      }
    }
    __builtin_amdgcn_s_setprio(0);
    int oo = o0 - 1024;
    for (int of = 0; of < 2; ++of) {
      int h = (oo + of * 16) >> 7, dr = ((oo + of * 16) & 127) + l15;
      float bvl = bv[oo + of * 16 + l15];
      for (int jt = 0; jt < 8; ++jt) {
        *(bf16x4*)(Vd + (((size_t)b * NH + h) * CD + dr) * HWN + n0 + jt * 16 + l4 * 4) =
            pk4(acc[of][jt][0] + bvl, acc[of][jt][1] + bvl,
                acc[of][jt][2] + bvl, acc[of][jt][3] + bvl);
      }
    }
  }
}

// ---- flash attention per (b,h): S=1024, D=128 ---------------------------
// R10-proven structure; R13: softmax max/sum restructured as trees (depth-5
// fmax tree + 4-way partial-sum tree) to cut the serial VALU dependency
// chain (~250 cyc/iter -> ~60). No memory/sync changes.
__launch_bounds__(256, 2)
__global__ void attn(const short* __restrict__ Qt, const short* __restrict__ Kt,
                     const short* __restrict__ Vd, short* __restrict__ Oscr) {
  int wid = blockIdx.x;
  int work = (wid & 7) * 64 + (wid >> 3);
  int xb = work & 7;
  int h = (work >> 3) & 3;
  int b = work >> 5;

  int wave = threadIdx.x >> 6, lane = threadIdx.x & 63;
  int l15 = lane & 15, l4 = lane >> 4;
  int q5 = lane & 31, hi = lane >> 5;
  int n0 = xb * 128 + wave * 32;
  size_t bh = (size_t)b * NH + h;
  const short* q = Qt + bh * HWN * CD;
  const short* k = Kt + bh * HWN * CD;
  const short* v = Vd + bh * CD * HWN;

  __shared__ short Kls[2][KVB * CD];  // 2 x 16 KB, rows XOR-swizzled (byte^=(row&7)<<4)
  __shared__ short Vls[2][CD * KVB];  // 2 x 16 KB, [d][m] rows XOR-swizzled likewise

#define STAGE(buf, m0s)                                                         \
  for (int j = 0; j < 4; ++j) {                                                 \
    int ii = wave * 4 + j;                                                      \
    int krow = ii * 4 + l4;                                                     \
    int kcol = (l15 * 16) ^ ((krow & 7) << 4);                                  \
    const short* kgp = k + (size_t)((m0s) + krow) * CD + (kcol >> 1);           \
    __builtin_amdgcn_global_load_lds(                                           \
        (const __attribute__((address_space(1))) void*)kgp,                     \
        (__attribute__((address_space(3))) void*)&Kls[buf][ii * 512], 16, 0, 0);\
    int vrow = ii * 8 + (lane >> 3);                                            \
    int vcol = ((lane & 7) * 16) ^ ((vrow & 7) << 4);                           \
    const short* vgp = v + (size_t)vrow * HWN + (m0s) + (vcol >> 1);            \
    __builtin_amdgcn_global_load_lds(                                           \
        (const __attribute__((address_space(1))) void*)vgp,                     \
        (__attribute__((address_space(3))) void*)&Vls[buf][ii * 512], 16, 0, 0);\
  }

  bf16x8 bq[8];
  for (int kt = 0; kt < 8; ++kt)
    bq[kt] = *(const bf16x8*)(q + (size_t)(n0 + q5) * CD + kt * 16 + hi * 8);

  f32x16 oacc[4];
  for (int dt = 0; dt < 4; ++dt)
#pragma unroll
    for (int r = 0; r < 16; ++r) oacc[dt][r] = 0.f;
  float mi = -1e30f, li = 0.f;

  STAGE(0, 0)
  __syncthreads();

  for (int mt = 0; mt < 16; ++mt) {
    int m0 = mt * KVB;
    int cur = mt & 1;
    if (mt < 15) STAGE(cur ^ 1, m0 + KVB)

    f32x16 s0, s1;
#pragma unroll
    for (int r = 0; r < 16; ++r) { s0[r] = 0.f; s1[r] = 0.f; }
    __builtin_amdgcn_s_setprio(1);
#pragma unroll
    for (int kt = 0; kt < 8; ++kt) {
      int col = kt * 16 + hi * 8;
      bf16x8 ak0 = *(const bf16x8*)&Kls[cur][q5 * CD + (col ^ ((q5 & 7) << 3))];
      bf16x8 ak1 = *(const bf16x8*)&Kls[cur][(32 + q5) * CD + (col ^ ((q5 & 7) << 3))];
      s0 = __builtin_amdgcn_mfma_f32_32x32x16_bf16(ak0, bq[kt], s0, 0, 0, 0);
      s1 = __builtin_amdgcn_mfma_f32_32x32x16_bf16(ak1, bq[kt], s1, 0, 0, 0);
    }
    __builtin_amdgcn_s_setprio(0);

    // row max: pairwise tree (depth 5) instead of 31-deep serial chain
    float t[16];
#pragma unroll
    for (int r = 0; r < 16; ++r) t[r] = fmaxf(s0[r], s1[r]);
#pragma unroll
    for (int w = 8; w > 0; w >>= 1)
#pragma unroll
      for (int r = 0; r < w; ++r) t[r] = fmaxf(t[r], t[r + w]);
    float mx = fmaxf(t[0], xswap32(t[0], lane));

    if (!__all(mx - mi <= 8.0f)) {
      float nm = fmaxf(mi, mx);
      float fac = __builtin_amdgcn_exp2f(mi - nm);
      mi = nm;
      li *= fac;
      for (int dt = 0; dt < 4; ++dt)
#pragma unroll
        for (int r = 0; r < 16; ++r) oacc[dt][r] *= fac;
    }
    // exp + sum: 4 independent partial chains, then small tree
    float ps[4] = {0.f, 0.f, 0.f, 0.f};
#pragma unroll
    for (int r = 0; r < 16; ++r) {
      float e0 = __builtin_amdgcn_exp2f(s0[r] - mi);
      float e1 = __builtin_amdgcn_exp2f(s1[r] - mi);
      s0[r] = e0; s1[r] = e1;
      ps[r & 3] += e0 + e1;
    }
    float ls = (ps[0] + ps[1]) + (ps[2] + ps[3]);
    ls += xswap32(ls, lane);
    li += ls;

    unsigned pkw[2][4][2];
#pragma unroll
    for (int g = 0; g < 4; ++g) {
      pkw[0][g][0] = pk2(s0[4 * g + 0], s0[4 * g + 1]);
      pkw[0][g][1] = pk2(s0[4 * g + 2], s0[4 * g + 3]);
      pkw[1][g][0] = pk2(s1[4 * g + 0], s1[4 * g + 1]);
      pkw[1][g][1] = pk2(s1[4 * g + 2], s1[4 * g + 3]);
    }
    bf16x8 pb[4];
#pragma unroll
    for (int ks = 0; ks < 4; ++ks) {
      int t2 = ks >> 1, G0 = 2 * (ks & 1);
      unsigned a0 = pkw[t2][G0][0], b0 = pkw[t2][G0 + 1][0];
      unsigned a1 = pkw[t2][G0][1], b1 = pkw[t2][G0 + 1][1];
      PSWAP(a0, b0);
      PSWAP(a1, b1);
      union { unsigned u[4]; bf16x8 v; } f;
      f.u[0] = a0; f.u[1] = a1; f.u[2] = b0; f.u[3] = b1;
      pb[ks] = f.v;
    }

    __builtin_amdgcn_s_setprio(1);
#pragma unroll
    for (int dt = 0; dt < 4; ++dt) {
      int d = dt * 32 + q5;
      const short* vb = &Vls[cur][d * KVB];
#pragma unroll
      for (int ks = 0; ks < 4; ++ks) {
        bf16x8 av = *(const bf16x8*)&vb[(ks * 16 + hi * 8) ^ ((d & 7) << 3)];
        oacc[dt] = __builtin_amdgcn_mfma_f32_32x32x16_bf16(av, pb[ks], oacc[dt], 0, 0, 0);
      }
    }
    __builtin_amdgcn_s_setprio(0);

    __syncthreads();
  }
#undef STAGE

  float inv = 1.0f / li;
  int n = n0 + q5;
  int o = h * CD + (n >> 3);
  size_t base = ((size_t)b * HWN + (n & 7) * CD) * 512 + o;
  for (int dt = 0; dt < 4; ++dt) {
#pragma unroll
    for (int r = 0; r < 16; ++r) {
      int d = dt * 32 + (r & 3) + 8 * (r >> 2) + 4 * hi;
      Oscr[base + (size_t)d * 512] = f2bf(oacc[dt][r] * inv);
    }
  }
}

// ---- proj: out[b][c][m] = x + bt[c] + sum_o Wt[c][o]*OscrT[m][o] --------
// R13: grid 1024 (bijective 8x128 XCD chunk swizzle), block = 16m x 128c,
// Ols tile 16KB -> 4-5 blocks/CU (was 2). Wave owns 16m x 32c.
__launch_bounds__(256)
__global__ void proj_kernel(const short* __restrict__ Oscr, const short* __restrict__ wtb,
                            const float* __restrict__ bt, const float* __restrict__ x,
                            float* __restrict__ out) {
  int wid = blockIdx.x;
  int work = (wid & 7) * 128 + (wid >> 3);  // bijective: 1024 = 8 * 128
  int b = work >> 6;
  int mt = work & 63;
  int m0b = mt * 16;

  int wave = threadIdx.x >> 6, lane = threadIdx.x & 63;
  int l15 = lane & 15, l4 = lane >> 4;
  int c0 = wave * 32;

  __shared__ short Ols[16 * 512];  // 16KB, rows XOR-swizzled (byte^=(row&7)<<4)

  // stage 16 rows x 1KB (one instruction per row), pre-swizzled source
  for (int j = 0; j < 4; ++j) {
    int row = wave * 4 + j;
    int scol = (lane * 16) ^ ((row & 7) << 4);
    const short* gp = Oscr + ((size_t)b * HWN + m0b + row) * 512 + (scol >> 1);
    __builtin_amdgcn_global_load_lds(
        (const __attribute__((address_space(1))) void*)gp,
        (__attribute__((address_space(3))) void*)&Ols[row * 512], 16, 0, 0);
  }

  f32x4 acc[2];
  acc[0] = (f32x4){0.f, 0.f, 0.f, 0.f};
  acc[1] = (f32x4){0.f, 0.f, 0.f, 0.f};

  __syncthreads();  // staging complete

  __builtin_amdgcn_s_setprio(1);
#pragma unroll
  for (int kt = 0; kt < 16; ++kt) {
    bf16x8 a = *(const bf16x8*)&Ols[l15 * 512 + ((kt * 32 + l4 * 8) ^ ((l15 & 7) << 3))];
#pragma unroll
    for (int jt = 0; jt < 2; ++jt) {
      bf16x8 bw = *(const bf16x8*)(wtb + (size_t)(c0 + jt * 16 + l15) * 512 + kt * 32 + l4 * 8);
      acc[jt] = __builtin_amdgcn_mfma_f32_16x16x32_bf16(a, bw, acc[jt], 0, 0, 0);
    }
  }
  __builtin_amdgcn_s_setprio(0);

  for (int jt = 0; jt < 2; ++jt) {
    int c = c0 + jt * 16 + l15;
    float btc = bt[c];
    size_t base = ((size_t)b * CD + c) * HWN + m0b + l4 * 4;
    f32x4 xr = *(const f32x4*)(x + base);
    f32x4 o;
    for (int r = 0; r < 4; ++r) o[r] = acc[jt][r] + xr[r] + btc;
    *(f32x4*)(out + base) = o;
  }
}

extern "C" void kernel_launch(void* const* d_in, const int* in_sizes, int n_in,
                              void* d_out, int out_size, void* d_ws, size_t ws_size,
                              hipStream_t stream) {
  const float* x  = (const float*)d_in[0];
  const float* Wq = (const float*)d_in[1];
  const float* Wk = (const float*)d_in[2];
  const float* Wv = (const float*)d_in[3];
  const float* bv = (const float*)d_in[4];
  const float* Wt = (const float*)d_in[5];
  const float* bt = (const float*)d_in[6];
  float* out = (float*)d_out;
  char* ws = (char*)d_ws;

  short* wqkv = (short*)(ws);
  short* wtb  = (short*)(ws + 393216);
  short* xt   = (short*)(ws + 524288);
  short* Qt   = (short*)(ws + 4718592);
  short* Kt   = (short*)(ws + 21495808);
  short* Vd   = (short*)(ws + 38273024);
  short* Oscr = (short*)(ws + 55050240);  // total 71827456 bytes

  hipLaunchKernelGGL(prep, dim3(32, 4, 17), dim3(256), 0, stream, x, Wq, Wk, Wv, Wt, wqkv, wtb, xt);
  hipLaunchKernelGGL(qkv_gemm, dim3(1536), dim3(256), 0, stream, wqkv, xt, bv, Qt, Kt, Vd);
  hipLaunchKernelGGL(attn, dim3(512), dim3(256), 0, stream, Qt, Kt, Vd, Oscr);
  hipLaunchKernelGGL(proj_kernel, dim3(1024), dim3(256), 0, stream, Oscr, wtb, bt, x, out);
}

// Round 17
// 100.702 us; speedup vs baseline: 1.0083x; 1.0083x over previous
//
#include <hip/hip_runtime.h>
#include <hip/hip_bf16.h>

// Conv2DAttentionBlock: B=16, C=128, HW=1024, 4 heads x d=128 attention + 1x1 convs.
// All GEMM-shaped stages in bf16 MFMA, fp32 accumulate.
// PROVEN-BEST configuration (R12: 100.8 us, absmax 0.031). Later rounds'
// epilogue/wave-structure experiments (R13-R16) were neutral or failed
// validation and are reverted.
// Workspace layout (needs 71,827,456 bytes):
//   wqkv  bf16[1536][128]           @ 0           (Wq rows pre-scaled by 1/sqrt(128)*log2e)
//   wtb   bf16[128][512]            @ 393216
//   xt    bf16[16][1024][128]       @ 524288      (x transposed, n-major)
//   Qt    bf16[16][4][1024][128]    @ 4718592     (n-major, pre-scaled)
//   Kt    bf16[16][4][1024][128]    @ 21495808    (m-major)
//   Vd    bf16[16][4][128][1024]    @ 38273024    (d-major)
//   Oscr  bf16[16][1024][512]       @ 55050240    (scrambled-transposed attn out)

#define NB 16
#define CD 128
#define HWN 1024
#define NH 4
#define KVB 64

typedef __attribute__((ext_vector_type(8))) short bf16x8;
typedef __attribute__((ext_vector_type(4))) short bf16x4;
typedef __attribute__((ext_vector_type(4))) float f32x4;
typedef __attribute__((ext_vector_type(16))) float f32x16;

static __device__ __forceinline__ short f2bf(float f) {
  union { float f; unsigned u; } v; v.f = f;
  unsigned r = v.u + 0x7fffu + ((v.u >> 16) & 1u);  // RNE
  return (short)(r >> 16);
}

// pack 2 f32 -> dword of 2 bf16 (lo = a, hi = b)
static __device__ __forceinline__ unsigned pk2(float a, float b) {
  unsigned r;
  asm("v_cvt_pk_bf16_f32 %0, %1, %2" : "=v"(r) : "v"(a), "v"(b));
  return r;
}

// pack 4 f32 -> 4 bf16
static __device__ __forceinline__ bf16x4 pk4(float a0, float a1, float a2, float a3) {
  union { unsigned u[2]; bf16x4 s; } r;
  r.u[0] = pk2(a0, a1);
  r.u[1] = pk2(a2, a3);
  return r.s;
}

// v_permlane32_swap_b32 a, b:  a' = {a_lo, b_lo},  b' = {a_hi, b_hi}
#define PSWAP(a, b) asm("v_permlane32_swap_b32 %0, %1" : "+v"(a), "+v"(b))

// exchange with lane^32: returns partner's x
static __device__ __forceinline__ float xswap32(float x, int lane) {
  union { float f; unsigned u; } a, b;
  a.f = x; b.f = x;
  PSWAP(a.u, b.u);
  return (lane < 32) ? b.f : a.f;
}

// ---- prep: weights fp32->bf16 (z==16) + x transpose (z<16) --------------
// Transpose write phase vectorized: each thread assembles bf16x4 from the
// padded LDS tile and does one 8B store (64B-contiguous per 8 lanes).
__global__ void prep(const float* __restrict__ x, const float* __restrict__ Wq,
                     const float* __restrict__ Wk, const float* __restrict__ Wv,
                     const float* __restrict__ Wt,
                     short* __restrict__ wqkv, short* __restrict__ wtb,
                     short* __restrict__ xt) {
  __shared__ short tile[32][33];  // tile[c_local][n_local], +1 pad
  if (blockIdx.z == 16) {
    const float SC = 0.08838834764831845f * 1.44269504088896341f;  // 1/sqrt(128)*log2(e)
    int gid = (blockIdx.x * 4 + blockIdx.y) * 256 + threadIdx.x;   // 0..32767
#pragma unroll
    for (int t = 0; t < 2; ++t) {
      int i = gid + t * 32768;
      wqkv[i]          = f2bf(Wq[i] * SC);
      wqkv[i + 65536]  = f2bf(Wk[i]);
      wqkv[i + 131072] = f2bf(Wv[i]);
      wtb[i]           = f2bf(Wt[i]);
    }
    return;
  }
  int b = blockIdx.z, c0 = blockIdx.y * 32, n0 = blockIdx.x * 32;
  int tx = threadIdx.x & 31, ty = threadIdx.x >> 5;  // 32x8
  const float* xp = x + ((size_t)b * CD + c0) * HWN + n0;
  for (int k = 0; k < 4; ++k)
    tile[ty + 8 * k][tx] = f2bf(xp[(size_t)(ty + 8 * k) * HWN + tx]);
  __syncthreads();
  // write: thread -> (n_local = t>>3, c_local = 4*(t&7)), one bf16x4 store
  int nl = threadIdx.x >> 3, cq = (threadIdx.x & 7) * 4;
  bf16x4 v4;
#pragma unroll
  for (int k = 0; k < 4; ++k) v4[k] = tile[cq + k][nl];
  *(bf16x4*)(xt + ((size_t)b * HWN + n0 + nl) * CD + c0 + cq) = v4;
}

// ---- QKV: Y[o][n] = sum_c Wqkv[o][c] * x[c][n]; scatter to Qt/Kt/Vd -----
// (R10-proven: LDS-staged x-tile, XCD chunk swizzle)
__launch_bounds__(256)
__global__ void qkv_gemm(const short* __restrict__ wqkv, const short* __restrict__ xt,
                         const float* __restrict__ bv,
                         short* __restrict__ Qt, short* __restrict__ Kt,
                         short* __restrict__ Vd) {
  int wid = blockIdx.x;
  int work = (wid & 7) * 192 + (wid >> 3);  // bijective: 1536 = 8 * 192
  int b = work / 96;
  int rem = work - b * 96;
  int oy = rem >> 3;   // 0..11 -> o-tile of 128
  int nx = rem & 7;    // 0..7  -> n-tile of 128

  int wave = threadIdx.x >> 6, lane = threadIdx.x & 63;
  int l15 = lane & 15, l4 = lane >> 4;
  int o0 = oy * 128 + wave * 32;
  int n0 = nx * 128;
  bool isV = (oy >= 8);  // uniform per block

  __shared__ short Xls[128 * CD];  // 32KB, rows XOR-swizzled (byte^=(row&7)<<4)

  for (int j = 0; j < 8; ++j) {
    int ii = wave * 8 + j;
    int row = ii * 4 + l4;
    int scol = (l15 * 16) ^ ((row & 7) << 4);
    const short* gp = xt + ((size_t)b * HWN + n0 + row) * CD + (scol >> 1);
    __builtin_amdgcn_global_load_lds(
        (const __attribute__((address_space(1))) void*)gp,
        (__attribute__((address_space(3))) void*)&Xls[ii * 512], 16, 0, 0);
  }

  bf16x8 afrag[2][4];
  for (int of = 0; of < 2; ++of)
    for (int kt = 0; kt < 4; ++kt)
      afrag[of][kt] = *(const bf16x8*)(wqkv + (size_t)(o0 + of * 16 + l15) * CD + kt * 32 + l4 * 8);

  f32x4 acc[2][8];
  for (int of = 0; of < 2; ++of)
    for (int jt = 0; jt < 8; ++jt) acc[of][jt] = (f32x4){0.f, 0.f, 0.f, 0.f};

  __syncthreads();  // staging complete (drains vmcnt)

  if (!isV) {
    __builtin_amdgcn_s_setprio(1);
    for (int jt = 0; jt < 8; ++jt) {
      int rb = (jt * 16 + l15) * CD;
      for (int kt = 0; kt < 4; ++kt) {
        bf16x8 bfrag = *(const bf16x8*)&Xls[rb + ((kt * 32 + l4 * 8) ^ ((l15 & 7) << 3))];
        acc[0][jt] = __builtin_amdgcn_mfma_f32_16x16x32_bf16(afrag[0][kt], bfrag, acc[0][jt], 0, 0, 0);
        acc[1][jt] = __builtin_amdgcn_mfma_f32_16x16x32_bf16(afrag[1][kt], bfrag, acc[1][jt], 0, 0, 0);
      }
    }
    __builtin_amdgcn_s_setprio(0);
    short* dst = (o0 < 512) ? Qt : Kt;
    int oo = (o0 < 512) ? o0 : o0 - 512;
    for (int of = 0; of < 2; ++of) {
      int h = (oo + of * 16) >> 7, d0 = ((oo + of * 16) & 127) + l4 * 4;
      for (int jt = 0; jt < 8; ++jt) {
        int n = n0 + jt * 16 + l15;
        *(bf16x4*)(dst + (((size_t)b * NH + h) * HWN + n) * CD + d0) =
            pk4(acc[of][jt][0], acc[of][jt][1], acc[of][jt][2], acc[of][jt][3]);
      }
    }
  } else {
    __builtin_amdgcn_s_setprio(1);
    for (int jt = 0; jt < 8; ++jt) {
      int rb = (jt * 16 + l15) * CD;
      for (int kt = 0; kt < 4; ++kt) {
        bf16x8 bfrag = *(const bf16x8*)&Xls[rb + ((kt * 32 + l4 * 8) ^ ((l15 & 7) << 3))];
        acc[0][jt] = __builtin_amdgcn_mfma_f32_16x16x32_bf16(bfrag, afrag[0][kt], acc[0][jt], 0, 0, 0);
        acc[1][jt] = __builtin_amdgcn_mfma_f32_16x16x32_bf16(bfrag, afrag[1][kt], acc[1][jt], 0, 0, 0);
      }
    }
    __builtin_amdgcn_s_setprio(0);
    int oo = o0 - 1024;
    for (int of = 0; of < 2; ++of) {
      int h = (oo + of * 16) >> 7, dr = ((oo + of * 16) & 127) + l15;
      float bvl = bv[oo + of * 16 + l15];
      for (int jt = 0; jt < 8; ++jt) {
        *(bf16x4*)(Vd + (((size_t)b * NH + h) * CD + dr) * HWN + n0 + jt * 16 + l4 * 4) =
            pk4(acc[of][jt][0] + bvl, acc[of][jt][1] + bvl,
                acc[of][jt][2] + bvl, acc[of][jt][3] + bvl);
      }
    }
  }
}

// ---- flash attention per (b,h): S=1024, D=128 ---------------------------
// R10-EXACT (proven): 32x32x16 MFMA pipeline; K+V staged in LDS (dbuf
// global_load_lds, XOR-swizzled via pre-swizzled source); swapped QK^T;
// per-lane softmax w/ one permlane32_swap; in-register P pack via
// cvt_pk+permlane; defer-max; setprio on MFMA clusters; XCD chunk swizzle.
__launch_bounds__(256, 2)
__global__ void attn(const short* __restrict__ Qt, const short* __restrict__ Kt,
                     const short* __restrict__ Vd, short* __restrict__ Oscr) {
  int wid = blockIdx.x;
  int work = (wid & 7) * 64 + (wid >> 3);
  int xb = work & 7;
  int h = (work >> 3) & 3;
  int b = work >> 5;

  int wave = threadIdx.x >> 6, lane = threadIdx.x & 63;
  int l15 = lane & 15, l4 = lane >> 4;
  int q5 = lane & 31, hi = lane >> 5;
  int n0 = xb * 128 + wave * 32;
  size_t bh = (size_t)b * NH + h;
  const short* q = Qt + bh * HWN * CD;
  const short* k = Kt + bh * HWN * CD;
  const short* v = Vd + bh * CD * HWN;

  __shared__ short Kls[2][KVB * CD];  // 2 x 16 KB, rows XOR-swizzled (byte^=(row&7)<<4)
  __shared__ short Vls[2][CD * KVB];  // 2 x 16 KB, [d][m] rows XOR-swizzled likewise

#define STAGE(buf, m0s)                                                         \
  for (int j = 0; j < 4; ++j) {                                                 \
    int ii = wave * 4 + j;                                                      \
    int krow = ii * 4 + l4;                                                     \
    int kcol = (l15 * 16) ^ ((krow & 7) << 4);                                  \
    const short* kgp = k + (size_t)((m0s) + krow) * CD + (kcol >> 1);           \
    __builtin_amdgcn_global_load_lds(                                           \
        (const __attribute__((address_space(1))) void*)kgp,                     \
        (__attribute__((address_space(3))) void*)&Kls[buf][ii * 512], 16, 0, 0);\
    int vrow = ii * 8 + (lane >> 3);                                            \
    int vcol = ((lane & 7) * 16) ^ ((vrow & 7) << 4);                           \
    const short* vgp = v + (size_t)vrow * HWN + (m0s) + (vcol >> 1);            \
    __builtin_amdgcn_global_load_lds(                                           \
        (const __attribute__((address_space(1))) void*)vgp,                     \
        (__attribute__((address_space(3))) void*)&Vls[buf][ii * 512], 16, 0, 0);\
  }

  bf16x8 bq[8];
  for (int kt = 0; kt < 8; ++kt)
    bq[kt] = *(const bf16x8*)(q + (size_t)(n0 + q5) * CD + kt * 16 + hi * 8);

  f32x16 oacc[4];
  for (int dt = 0; dt < 4; ++dt)
#pragma unroll
    for (int r = 0; r < 16; ++r) oacc[dt][r] = 0.f;
  float mi = -1e30f, li = 0.f;

  STAGE(0, 0)
  __syncthreads();

  for (int mt = 0; mt < 16; ++mt) {
    int m0 = mt * KVB;
    int cur = mt & 1;
    if (mt < 15) STAGE(cur ^ 1, m0 + KVB)

    f32x16 s0, s1;
#pragma unroll
    for (int r = 0; r < 16; ++r) { s0[r] = 0.f; s1[r] = 0.f; }
    __builtin_amdgcn_s_setprio(1);
#pragma unroll
    for (int kt = 0; kt < 8; ++kt) {
      int col = kt * 16 + hi * 8;
      bf16x8 ak0 = *(const bf16x8*)&Kls[cur][q5 * CD + (col ^ ((q5 & 7) << 3))];
      bf16x8 ak1 = *(const bf16x8*)&Kls[cur][(32 + q5) * CD + (col ^ ((q5 & 7) << 3))];
      s0 = __builtin_amdgcn_mfma_f32_32x32x16_bf16(ak0, bq[kt], s0, 0, 0, 0);
      s1 = __builtin_amdgcn_mfma_f32_32x32x16_bf16(ak1, bq[kt], s1, 0, 0, 0);
    }
    __builtin_amdgcn_s_setprio(0);

    float mx = s0[0];
#pragma unroll
    for (int r = 1; r < 16; ++r) mx = fmaxf(mx, s0[r]);
#pragma unroll
    for (int r = 0; r < 16; ++r) mx = fmaxf(mx, s1[r]);
    mx = fmaxf(mx, xswap32(mx, lane));

    if (!__all(mx - mi <= 8.0f)) {
      float nm = fmaxf(mi, mx);
      float fac = __builtin_amdgcn_exp2f(mi - nm);
      mi = nm;
      li *= fac;
      for (int dt = 0; dt < 4; ++dt)
#pragma unroll
        for (int r = 0; r < 16; ++r) oacc[dt][r] *= fac;
    }
    float ls = 0.f;
#pragma unroll
    for (int r = 0; r < 16; ++r) {
      float e0 = __builtin_amdgcn_exp2f(s0[r] - mi);
      float e1 = __builtin_amdgcn_exp2f(s1[r] - mi);
      s0[r] = e0; s1[r] = e1;
      ls += e0 + e1;
    }
    ls += xswap32(ls, lane);
    li += ls;

    unsigned pkw[2][4][2];
#pragma unroll
    for (int g = 0; g < 4; ++g) {
      pkw[0][g][0] = pk2(s0[4 * g + 0], s0[4 * g + 1]);
      pkw[0][g][1] = pk2(s0[4 * g + 2], s0[4 * g + 3]);
      pkw[1][g][0] = pk2(s1[4 * g + 0], s1[4 * g + 1]);
      pkw[1][g][1] = pk2(s1[4 * g + 2], s1[4 * g + 3]);
    }
    bf16x8 pb[4];
#pragma unroll
    for (int ks = 0; ks < 4; ++ks) {
      int t2 = ks >> 1, G0 = 2 * (ks & 1);
      unsigned a0 = pkw[t2][G0][0], b0 = pkw[t2][G0 + 1][0];
      unsigned a1 = pkw[t2][G0][1], b1 = pkw[t2][G0 + 1][1];
      PSWAP(a0, b0);
      PSWAP(a1, b1);
      union { unsigned u[4]; bf16x8 v; } f;
      f.u[0] = a0; f.u[1] = a1; f.u[2] = b0; f.u[3] = b1;
      pb[ks] = f.v;
    }

    __builtin_amdgcn_s_setprio(1);
#pragma unroll
    for (int dt = 0; dt < 4; ++dt) {
      int d = dt * 32 + q5;
      const short* vb = &Vls[cur][d * KVB];
#pragma unroll
      for (int ks = 0; ks < 4; ++ks) {
        bf16x8 av = *(const bf16x8*)&vb[(ks * 16 + hi * 8) ^ ((d & 7) << 3)];
        oacc[dt] = __builtin_amdgcn_mfma_f32_32x32x16_bf16(av, pb[ks], oacc[dt], 0, 0, 0);
      }
    }
    __builtin_amdgcn_s_setprio(0);

    __syncthreads();
  }
#undef STAGE

  float inv = 1.0f / li;
  int n = n0 + q5;
  int o = h * CD + (n >> 3);
  size_t base = ((size_t)b * HWN + (n & 7) * CD) * 512 + o;
  for (int dt = 0; dt < 4; ++dt) {
#pragma unroll
    for (int r = 0; r < 16; ++r) {
      int d = dt * 32 + (r & 3) + 8 * (r >> 2) + 4 * hi;
      Oscr[base + (size_t)d * 512] = f2bf(oacc[dt][r] * inv);
    }
  }
}

// ---- proj: out[b][c][m] = x + bt[c] + sum_o Wt[c][o]*OscrT[m][o] --------
// (R12-proven: grid 512, 32m x 512o Ols tile, wave = 16m x 64c)
__launch_bounds__(256)
__global__ void proj_kernel(const short* __restrict__ Oscr, const short* __restrict__ wtb,
                            const float* __restrict__ bt, const float* __restrict__ x,
                            float* __restrict__ out) {
  int wid = blockIdx.x;
  int work = (wid & 7) * 64 + (wid >> 3);  // bijective: 512 = 8 * 64
  int b = work >> 5;
  int mx = work & 31;

  int wave = threadIdx.x >> 6, lane = threadIdx.x & 63;
  int l15 = lane & 15, l4 = lane >> 4;
  int m0b = mx * 32;
  int mloc = (wave & 1) * 16;
  int c0 = (wave >> 1) * 64;

  __shared__ short Ols[32 * 512];  // 32KB, rows XOR-swizzled (byte^=(row&7)<<4)

  for (int j = 0; j < 8; ++j) {
    int row = wave * 8 + j;
    int scol = (lane * 16) ^ ((row & 7) << 4);
    const short* gp = Oscr + ((size_t)b * HWN + m0b + row) * 512 + (scol >> 1);
    __builtin_amdgcn_global_load_lds(
        (const __attribute__((address_space(1))) void*)gp,
        (__attribute__((address_space(3))) void*)&Ols[row * 512], 16, 0, 0);
  }

  f32x4 acc[4];
  for (int jt = 0; jt < 4; ++jt) acc[jt] = (f32x4){0.f, 0.f, 0.f, 0.f};

  __syncthreads();  // staging complete

  __builtin_amdgcn_s_setprio(1);
  for (int kt = 0; kt < 16; ++kt) {
    bf16x8 a = *(const bf16x8*)&Ols[(mloc + l15) * 512 + ((kt * 32 + l4 * 8) ^ ((l15 & 7) << 3))];
    for (int jt = 0; jt < 4; ++jt) {
      bf16x8 bw = *(const bf16x8*)(wtb + (size_t)(c0 + jt * 16 + l15) * 512 + kt * 32 + l4 * 8);
      acc[jt] = __builtin_amdgcn_mfma_f32_16x16x32_bf16(a, bw, acc[jt], 0, 0, 0);
    }
  }
  __builtin_amdgcn_s_setprio(0);

  for (int jt = 0; jt < 4; ++jt) {
    int c = c0 + jt * 16 + l15;
    float btc = bt[c];
    size_t base = ((size_t)b * CD + c) * HWN + m0b + mloc + l4 * 4;
    f32x4 xr = *(const f32x4*)(x + base);
    f32x4 o;
    for (int r = 0; r < 4; ++r) o[r] = acc[jt][r] + xr[r] + btc;
    *(f32x4*)(out + base) = o;
  }
}

extern "C" void kernel_launch(void* const* d_in, const int* in_sizes, int n_in,
                              void* d_out, int out_size, void* d_ws, size_t ws_size,
                              hipStream_t stream) {
  const float* x  = (const float*)d_in[0];
  const float* Wq = (const float*)d_in[1];
  const float* Wk = (const float*)d_in[2];
  const float* Wv = (const float*)d_in[3];
  const float* bv = (const float*)d_in[4];
  const float* Wt = (const float*)d_in[5];
  const float* bt = (const float*)d_in[6];
  float* out = (float*)d_out;
  char* ws = (char*)d_ws;

  short* wqkv = (short*)(ws);
  short* wtb  = (short*)(ws + 393216);
  short* xt   = (short*)(ws + 524288);
  short* Qt   = (short*)(ws + 4718592);
  short* Kt   = (short*)(ws + 21495808);
  short* Vd   = (short*)(ws + 38273024);
  short* Oscr = (short*)(ws + 55050240);  // total 71827456 bytes

  hipLaunchKernelGGL(prep, dim3(32, 4, 17), dim3(256), 0, stream, x, Wq, Wk, Wv, Wt, wqkv, wtb, xt);
  hipLaunchKernelGGL(qkv_gemm, dim3(1536), dim3(256), 0, stream, wqkv, xt, bv, Qt, Kt, Vd);
  hipLaunchKernelGGL(attn, dim3(512), dim3(256), 0, stream, Qt, Kt, Vd, Oscr);
  hipLaunchKernelGGL(proj_kernel, dim3(512), dim3(256), 0, stream, Oscr, wtb, bt, x, out);
}